// Round 4
// baseline (428.350 us; speedup 1.0000x reference)
//
#include <hip/hip_runtime.h>

typedef __bf16 bf16;
typedef __attribute__((ext_vector_type(8))) __bf16 bf16x8;
typedef __attribute__((ext_vector_type(4))) __bf16 bf16x4;
typedef __attribute__((ext_vector_type(4))) float f32x4;
typedef __attribute__((ext_vector_type(4))) short short4v;
typedef __attribute__((ext_vector_type(4))) unsigned int u32x4;

// ---- constants for this problem ----
#define BB 2
#define TT 2048
#define DD 2048
#define HH 16
#define HKV 4
#define DHD 128
#define NQKV 3072   // H*DH + 2*HKV*DH
#define NQK 2560    // q+k features (stored to Craw)

__device__ __forceinline__ void gl_lds16(const bf16* g, bf16* l) {
    __builtin_amdgcn_global_load_lds(
        (const __attribute__((address_space(1))) void*)g,
        (__attribute__((address_space(3))) void*)l, 16, 0, 0);
}

__device__ __forceinline__ f32x4 mfma16bf16(short4v a, short4v b, f32x4 c) {
#if defined(__HIP_DEVICE_COMPILE__)
    return __builtin_amdgcn_mfma_f32_16x16x16bf16_1k(a, b, c, 0, 0, 0);
#else
    return c;  // host pass never executes device code
#endif
}

// ---------------- fp32 -> bf16 convert ----------------
__global__ void cvt_bf16(const float* __restrict__ src, bf16* __restrict__ dst, int n8) {
    int i = blockIdx.x * 256 + threadIdx.x;
    if (i >= n8) return;
    float4 a = ((const float4*)src)[i * 2];
    float4 b = ((const float4*)src)[i * 2 + 1];
    bf16x8 v;
    v[0] = (bf16)a.x; v[1] = (bf16)a.y; v[2] = (bf16)a.z; v[3] = (bf16)a.w;
    v[4] = (bf16)b.x; v[5] = (bf16)b.y; v[6] = (bf16)b.z; v[7] = (bf16)b.w;
    *(bf16x8*)(dst + (size_t)i * 8) = v;
}

// ---------------- GEMM: C = A(MxK) * Bw(NxK)^T, bf16 in, fp32 acc ----------------
template <int MODE>
__global__ void gemm_bt(const bf16* __restrict__ A, const bf16* __restrict__ Bw,
                        int M, int N, int K,
                        float* __restrict__ Cout,
                        bf16* __restrict__ vT,
                        const float* __restrict__ v1,
                        const float* __restrict__ lamp) {
    __shared__ bf16 As[128 * 32];
    __shared__ bf16 Bs[128 * 32];
    const int tid = threadIdx.x;
    const int w = tid >> 6, lane = tid & 63;
    const int l15 = lane & 15, quad = lane >> 4;
    const int m0 = blockIdx.y * 128, n0 = blockIdx.x * 128;
    const int wm = (w & 1) * 64, wn = (w >> 1) * 64;

    f32x4 acc[4][4] = {};

    const int lrow = lane >> 2;          // 0..15 within chunk
    const int lcol = (lane & 3) * 8;     // bf16 elems

    for (int k0 = 0; k0 < K; k0 += 32) {
#pragma unroll
        for (int i = 0; i < 2; i++) {
            int c = w * 2 + i;
            int row = c * 16 + lrow;
            gl_lds16(A + (size_t)(m0 + row) * K + k0 + lcol, As + c * 512);
        }
#pragma unroll
        for (int i = 0; i < 2; i++) {
            int c = w * 2 + i;
            int row = c * 16 + lrow;
            gl_lds16(Bw + (size_t)(n0 + row) * K + k0 + lcol, Bs + c * 512);
        }
        __syncthreads();
        bf16x8 af[4], bfr[4];
#pragma unroll
        for (int mi = 0; mi < 4; mi++)
            af[mi] = *(const bf16x8*)(As + (wm + mi * 16 + l15) * 32 + quad * 8);
#pragma unroll
        for (int ni = 0; ni < 4; ni++)
            bfr[ni] = *(const bf16x8*)(Bs + (wn + ni * 16 + l15) * 32 + quad * 8);
#pragma unroll
        for (int mi = 0; mi < 4; mi++)
#pragma unroll
            for (int ni = 0; ni < 4; ni++)
                acc[mi][ni] = __builtin_amdgcn_mfma_f32_16x16x32_bf16(af[mi], bfr[ni], acc[mi][ni], 0, 0, 0);
        __syncthreads();
    }

    float lam = 0.f;
    if constexpr (MODE == 1) lam = lamp[0];

#pragma unroll
    for (int mi = 0; mi < 4; mi++)
#pragma unroll
        for (int ni = 0; ni < 4; ni++)
#pragma unroll
            for (int r = 0; r < 4; r++) {
                int m = m0 + wm + mi * 16 + quad * 4 + r;
                int n = n0 + wn + ni * 16 + l15;
                float val = acc[mi][ni][r];
                if constexpr (MODE == 0) {
                    Cout[(size_t)m * N + n] = val;
                } else {
                    if (n < NQK) {
                        Cout[(size_t)m * NQK + n] = val;
                    } else {
                        int f2 = n - NQK;
                        int hk = f2 >> 7, d = f2 & 127;
                        int b = m >> 11, t = m & (TT - 1);
                        size_t i1 = ((size_t)(b * HKV + hk) * TT + t) * DHD + d;
                        float vm = val + lam * (v1[i1] - val);
                        vT[((size_t)(b * HKV + hk) * DHD + d) * TT + t] = (bf16)vm;
                    }
                }
            }
}

// ---------------- RMSNorm + ortho RoPE, wave per (token, head) ----------------
// q heads get softmax scale * log2(e) pre-folded (fattn uses exp2).
__global__ void rmsrope(const float* __restrict__ Craw, const float* __restrict__ cosb,
                        const float* __restrict__ sinb, bf16* __restrict__ qb,
                        bf16* __restrict__ kb) {
    const float QSCALE = 0.08838834764831845f * 1.4426950408889634f;
    int gw = blockIdx.x * 4 + (threadIdx.x >> 6);
    int lane = threadIdx.x & 63;
    int token = gw / 20, hh = gw % 20;  // 0..15 q heads, 16..19 k heads
    int b = token >> 11, t = token & (TT - 1);
    int off = (hh < HH) ? hh * DHD : (HH * DHD + (hh - HH) * DHD);
    const float* src = Craw + (size_t)token * NQK + off;
    float2 xv = *(const float2*)(src + lane * 2);
    float x0 = xv.x, x1 = xv.y;
    float ss = x0 * x0 + x1 * x1;
#pragma unroll
    for (int m = 1; m < 64; m <<= 1) ss += __shfl_xor(ss, m);
    float r = rsqrtf(ss * (1.f / 128.f) + 1e-6f);
    if (hh < HH) r *= QSCALE;
    x0 *= r; x1 *= r;
    float c = cosb[t * 64 + lane], s = sinb[t * 64 + lane];
    float y0 = x0 * c - x1 * s;
    float y1 = x1 * c + x0 * s;
    bf16* dst = (hh < HH) ? (qb + ((size_t)(b * HH + hh) * TT + t) * DHD)
                          : (kb + ((size_t)(b * HKV + (hh - HH)) * TT + t) * DHD);
    dst[lane] = (bf16)y0;
    dst[64 + lane] = (bf16)y1;
}

// ---------------- gates = sigmoid(x[:, :16] @ gate_w^T) ----------------
__global__ void gatesk(const float* __restrict__ x, const float* __restrict__ gw,
                       float* __restrict__ gates) {
    __shared__ float gws[256];
    gws[threadIdx.x] = gw[threadIdx.x];
    __syncthreads();
    int idx = blockIdx.x * 256 + threadIdx.x;
    int h = idx & 15, token = idx >> 4;
    const float* xr = x + (size_t)token * DD;
    float z = 0.f;
#pragma unroll
    for (int j = 0; j < 16; j++) z += xr[j] * gws[h * 16 + j];
    gates[idx] = 1.f / (1.f + __expf(-z));
}

// ---------------- flash attention ----------------
// 256 blocks (1/CU). Block: (b,h) x 4 q-tiles {g,15-g,16+g,31-g} (64 rows each).
// Wave w owns rows w*16.. of each tile (4 subtiles = 64 q rows/wave).
// S computed TRANSPOSED (A=K, B=Q) so P (S^T C-layout: k=quad*4+r, q=l15)
// is directly the B-fragment of mfma_f32_16x16x16bf16 (k=quad*4+j) -> no
// cross-lane transform for PV. K/VT fragments loaded once/round into regs,
// shared by all 4 subtiles.
__global__ __launch_bounds__(256, 1) void fattn(const bf16* __restrict__ qbuf,
                                                const bf16* __restrict__ kbuf,
                                                const bf16* __restrict__ vt,
                                                const float* __restrict__ gates,
                                                bf16* __restrict__ yb) {
    // K  : [buf][kc:4][row:64][32]   (bf16)
    // VT : [buf][ni:4][d:128][16]    (bf16)
    __shared__ bf16 Ks[2][4 * 2048];
    __shared__ bf16 VTs[2][4 * 2048];

    const int bid = blockIdx.x;          // 256 blocks
    const int bh = bid & 31;             // b*16+h
    const int g = bid >> 5;              // 0..7
    const int h = bh & 15, b = bh >> 4;
    const int hk = h >> 2;
    const int tid = threadIdx.x, w = tid >> 6, lane = tid & 63;
    const int l15 = lane & 15, quad = lane >> 4;

    const bf16* qbase = qbuf + ((size_t)(b * HH + h) * TT) * DHD;
    const bf16* kbase = kbuf + ((size_t)(b * HKV + hk) * TT) * DHD;
    const bf16* vtbase = vt + ((size_t)(b * HKV + hk) * DHD) * TT;

    int Tq[4] = {g, 15 - g, 16 + g, 31 - g};
    const int ktmax = 31 - g;

    // Q B-fragments (q = Tq[st]*64 + w*16 + l15, k = kc*32 + quad*8), read once
    bf16x8 qf[4][4];
#pragma unroll
    for (int st = 0; st < 4; st++)
#pragma unroll
        for (int kc = 0; kc < 4; kc++)
            qf[st][kc] = *(const bf16x8*)(qbase + (size_t)(Tq[st] * 64 + w * 16 + l15) * DHD + kc * 32 + quad * 8);

    // diag masks: kg_off = ni*16 + quad*4 + r vs q_off = w*16 + l15 (loop-invariant)
    bool dm[4][4];
#pragma unroll
    for (int ni = 0; ni < 4; ni++)
#pragma unroll
        for (int r = 0; r < 4; r++)
            dm[ni][r] = (ni * 16 + quad * 4 + r) > (w * 16 + l15);

    const int srow = lane >> 2;          // K staging: row within 16-group
    const int scg = (lane & 3) * 8;      // K staging: col offset
    const int vd = lane >> 1;            // VT staging: d within 32-group
    const int vh = (lane & 1) * 8;       // VT staging: t offset

    auto stage = [&](int kt, int buf) {
#pragma unroll
        for (int i = 0; i < 4; i++) {
            gl_lds16(kbase + (size_t)(kt * 64 + w * 16 + srow) * DHD + i * 32 + scg,
                     &Ks[buf][i * 2048 + w * 512]);
            gl_lds16(vtbase + (size_t)(w * 32 + vd) * TT + kt * 64 + i * 16 + vh,
                     &VTs[buf][i * 2048 + w * 512]);
        }
    };

    stage(0, 0);

    f32x4 Ot[4][8] = {};
    float mr[4], lr[4];
#pragma unroll
    for (int st = 0; st < 4; st++) { mr[st] = -INFINITY; lr[st] = 0.f; }

    for (int kt = 0; kt <= ktmax; kt++) {
        int cur = kt & 1;
        __syncthreads();                 // drains prefetch into buf `cur`
        if (kt < ktmax) stage(kt + 1, cur ^ 1);

        // K A-fragments (rows ni*16+l15, k = kc*32+quad*8): 16 b128, shared by 4 subtiles
        bf16x8 kf[4][4];
#pragma unroll
        for (int ni = 0; ni < 4; ni++)
#pragma unroll
            for (int kc = 0; kc < 4; kc++)
                kf[ni][kc] = *(const bf16x8*)(&Ks[cur][kc * 2048 + (ni * 16 + l15) * 32 + quad * 8]);

        // VT A-fragments for 16x16x16 (d = dn*16+l15, t = ni*16+quad*4+j): 32 b64, shared
        short4v vf[4][8];
#pragma unroll
        for (int ni = 0; ni < 4; ni++)
#pragma unroll
            for (int dn = 0; dn < 8; dn++)
                vf[ni][dn] = *(const short4v*)(&VTs[cur][ni * 2048 + (dn * 16 + l15) * 16 + quad * 4]);

#pragma unroll
        for (int st = 0; st < 4; st++) {
            if (kt > Tq[st]) continue;   // wave-uniform

            // S^T = K Q^T : rows k (64), cols q (16)
            f32x4 sacc[4];
#pragma unroll
            for (int ni = 0; ni < 4; ni++) {
                f32x4 z = {};
#pragma unroll
                for (int kc = 0; kc < 4; kc++)
                    z = __builtin_amdgcn_mfma_f32_16x16x32_bf16(kf[ni][kc], qf[st][kc], z, 0, 0, 0);
                sacc[ni] = z;
            }

            float sv[4][4];
#pragma unroll
            for (int ni = 0; ni < 4; ni++)
#pragma unroll
                for (int r = 0; r < 4; r++) sv[ni][r] = sacc[ni][r];
            if (kt == Tq[st]) {
#pragma unroll
                for (int ni = 0; ni < 4; ni++)
#pragma unroll
                    for (int r = 0; r < 4; r++)
                        if (dm[ni][r]) sv[ni][r] = -INFINITY;
            }

            float mx = sv[0][0];
#pragma unroll
            for (int ni = 0; ni < 4; ni++)
#pragma unroll
                for (int r = 0; r < 4; r++) mx = fmaxf(mx, sv[ni][r]);
            mx = fmaxf(mx, __shfl_xor(mx, 16));
            mx = fmaxf(mx, __shfl_xor(mx, 32));
            float mold = mr[st];
            float mnew = fmaxf(mold, mx);

            float pv[4][4];
            float rs = 0.f;
#pragma unroll
            for (int ni = 0; ni < 4; ni++)
#pragma unroll
                for (int r = 0; r < 4; r++) {
                    float pe = __builtin_amdgcn_exp2f(sv[ni][r] - mnew);
                    pv[ni][r] = pe;
                    rs += pe;
                }
            rs += __shfl_xor(rs, 16);
            rs += __shfl_xor(rs, 32);

            if (__any(mnew > mold)) {
                float al = __builtin_amdgcn_exp2f(mold - mnew);
                lr[st] *= al;
#pragma unroll
                for (int dn = 0; dn < 8; dn++)
#pragma unroll
                    for (int r = 0; r < 4; r++) Ot[st][dn][r] *= al;
            }
            lr[st] += rs;
            mr[st] = mnew;

            // PV: O^T += VT * P^T, P directly in B-frag layout of 16x16x16
#pragma unroll
            for (int ni = 0; ni < 4; ni++) {
                union { bf16x4 h; short4v s; } bp;
                bp.h[0] = (bf16)pv[ni][0]; bp.h[1] = (bf16)pv[ni][1];
                bp.h[2] = (bf16)pv[ni][2]; bp.h[3] = (bf16)pv[ni][3];
#pragma unroll
                for (int dn = 0; dn < 8; dn++)
                    Ot[st][dn] = mfma16bf16(vf[ni][dn], bp.s, Ot[st][dn]);
            }
        }
    }

    // epilogue: O^T/l * gate -> yb (B,T,H*DH) bf16. Lane holds q (col l15) per st,
    // d rows dn*16 + quad*4 + {0..3} -> 8B packed stores.
#pragma unroll
    for (int st = 0; st < 4; st++) {
        int qg = Tq[st] * 64 + w * 16 + l15;
        float gi = gates[((size_t)b * TT + qg) * HH + h] / lr[st];
#pragma unroll
        for (int dn = 0; dn < 8; dn++) {
            bf16x4 o;
#pragma unroll
            for (int r = 0; r < 4; r++) o[r] = (bf16)(Ot[st][dn][r] * gi);
            *(bf16x4*)(yb + ((size_t)(b * TT + qg) * HH + h) * DHD + dn * 16 + quad * 4) = o;
        }
    }
}

extern "C" void kernel_launch(void* const* d_in, const int* in_sizes, int n_in,
                              void* d_out, int out_size, void* d_ws, size_t ws_size,
                              hipStream_t stream) {
    const float* x    = (const float*)d_in[0];
    const float* cosb = (const float*)d_in[2];
    const float* sinb = (const float*)d_in[3];
    const float* v1   = (const float*)d_in[4];
    const float* Wq   = (const float*)d_in[5];
    const float* Wk   = (const float*)d_in[6];
    const float* Wv   = (const float*)d_in[7];
    const float* Wo   = (const float*)d_in[8];
    const float* gw   = (const float*)d_in[9];
    const float* lam  = (const float*)d_in[10];
    float* out = (float*)d_out;

    char* ws = (char*)d_ws;
    bf16* xb     = (bf16*)(ws);                   // 16,777,216 B (reused later by yb)
    bf16* wqkvb  = (bf16*)(ws + 16777216);        // 12,582,912
    bf16* wob    = (bf16*)(ws + 29360128);        //  8,388,608
    float* Craw  = (float*)(ws + 37748736);       // 41,943,040 (4096 x 2560 fp32)
    bf16* qb     = (bf16*)(ws + 79691776);        // 16,777,216
    bf16* kb     = (bf16*)(ws + 96468992);        //  4,194,304
    bf16* vtb    = (bf16*)(ws + 100663296);       //  4,194,304
    float* gts   = (float*)(ws + 104857600);      //    262,144
    bf16* yb     = xb;                            // alias: xb dead after QKV GEMM

    // converts
    cvt_bf16<<<4096, 256, 0, stream>>>(x, xb, 1048576);
    cvt_bf16<<<2048, 256, 0, stream>>>(Wq, wqkvb, 524288);
    cvt_bf16<<<512, 256, 0, stream>>>(Wk, wqkvb + 4194304, 131072);
    cvt_bf16<<<512, 256, 0, stream>>>(Wv, wqkvb + 5242880, 131072);
    cvt_bf16<<<2048, 256, 0, stream>>>(Wo, wob, 524288);

    // QKV projection (writes Craw for q/k, mixed+transposed bf16 V)
    gemm_bt<1><<<dim3(24, 32), 256, 0, stream>>>(xb, wqkvb, 4096, NQKV, 2048,
                                                 Craw, vtb, v1, lam);
    // rmsnorm + rope -> bf16 q/k (q pre-scaled by scale*log2e)
    rmsrope<<<20480, 256, 0, stream>>>(Craw, cosb, sinb, qb, kb);
    // gates
    gatesk<<<256, 256, 0, stream>>>(x, gw, gts);
    // flash attention (4 subtiles/wave, reg-shared K/VT frags) -- yb aliases xb
    fattn<<<256, 256, 0, stream>>>(qb, kb, vtb, gts, yb);
    // output projection
    gemm_bt<0><<<dim3(16, 32), 256, 0, stream>>>(yb, wob, 4096, 2048, 2048,
                                                 out, nullptr, nullptr, nullptr);
    // v1 passthrough (second tuple output)
    (void)hipMemcpyAsync(out + 8388608, v1, (size_t)2097152 * sizeof(float),
                         hipMemcpyDeviceToDevice, stream);
}

// Round 5
// 400.564 us; speedup vs baseline: 1.0694x; 1.0694x over previous
//
#include <hip/hip_runtime.h>

typedef __bf16 bf16;
typedef __attribute__((ext_vector_type(8))) __bf16 bf16x8;
typedef __attribute__((ext_vector_type(4))) __bf16 bf16x4;
typedef __attribute__((ext_vector_type(4))) float f32x4;
typedef __attribute__((ext_vector_type(4))) short short4v;
typedef __attribute__((ext_vector_type(4))) unsigned int u32x4;

// ---- constants for this problem ----
#define BB 2
#define TT 2048
#define DD 2048
#define HH 16
#define HKV 4
#define DHD 128
#define NQKV 3072   // H*DH + 2*HKV*DH
#define NQK 2560    // q+k features (stored to Craw)

__device__ __forceinline__ void gl_lds16(const bf16* g, bf16* l) {
    __builtin_amdgcn_global_load_lds(
        (const __attribute__((address_space(1))) void*)g,
        (__attribute__((address_space(3))) void*)l, 16, 0, 0);
}

__device__ __forceinline__ f32x4 mfma16bf16(short4v a, short4v b, f32x4 c) {
#if defined(__HIP_DEVICE_COMPILE__)
    return __builtin_amdgcn_mfma_f32_16x16x16bf16_1k(a, b, c, 0, 0, 0);
#else
    return c;  // host pass never executes device code
#endif
}

// ---------------- fp32 -> bf16 convert ----------------
__global__ void cvt_bf16(const float* __restrict__ src, bf16* __restrict__ dst, int n8) {
    int i = blockIdx.x * 256 + threadIdx.x;
    if (i >= n8) return;
    float4 a = ((const float4*)src)[i * 2];
    float4 b = ((const float4*)src)[i * 2 + 1];
    bf16x8 v;
    v[0] = (bf16)a.x; v[1] = (bf16)a.y; v[2] = (bf16)a.z; v[3] = (bf16)a.w;
    v[4] = (bf16)b.x; v[5] = (bf16)b.y; v[6] = (bf16)b.z; v[7] = (bf16)b.w;
    *(bf16x8*)(dst + (size_t)i * 8) = v;
}

// ---------------- GEMM: C = A(MxK) * Bw(NxK)^T, bf16 in, fp32 acc ----------------
template <int MODE>
__global__ void gemm_bt(const bf16* __restrict__ A, const bf16* __restrict__ Bw,
                        int M, int N, int K,
                        float* __restrict__ Cout,
                        bf16* __restrict__ vT,
                        const float* __restrict__ v1,
                        const float* __restrict__ lamp) {
    __shared__ bf16 As[128 * 32];
    __shared__ bf16 Bs[128 * 32];
    const int tid = threadIdx.x;
    const int w = tid >> 6, lane = tid & 63;
    const int l15 = lane & 15, quad = lane >> 4;
    const int m0 = blockIdx.y * 128, n0 = blockIdx.x * 128;
    const int wm = (w & 1) * 64, wn = (w >> 1) * 64;

    f32x4 acc[4][4] = {};

    const int lrow = lane >> 2;          // 0..15 within chunk
    const int lcol = (lane & 3) * 8;     // bf16 elems

    for (int k0 = 0; k0 < K; k0 += 32) {
#pragma unroll
        for (int i = 0; i < 2; i++) {
            int c = w * 2 + i;
            int row = c * 16 + lrow;
            gl_lds16(A + (size_t)(m0 + row) * K + k0 + lcol, As + c * 512);
        }
#pragma unroll
        for (int i = 0; i < 2; i++) {
            int c = w * 2 + i;
            int row = c * 16 + lrow;
            gl_lds16(Bw + (size_t)(n0 + row) * K + k0 + lcol, Bs + c * 512);
        }
        __syncthreads();
        bf16x8 af[4], bfr[4];
#pragma unroll
        for (int mi = 0; mi < 4; mi++)
            af[mi] = *(const bf16x8*)(As + (wm + mi * 16 + l15) * 32 + quad * 8);
#pragma unroll
        for (int ni = 0; ni < 4; ni++)
            bfr[ni] = *(const bf16x8*)(Bs + (wn + ni * 16 + l15) * 32 + quad * 8);
#pragma unroll
        for (int mi = 0; mi < 4; mi++)
#pragma unroll
            for (int ni = 0; ni < 4; ni++)
                acc[mi][ni] = __builtin_amdgcn_mfma_f32_16x16x32_bf16(af[mi], bfr[ni], acc[mi][ni], 0, 0, 0);
        __syncthreads();
    }

    float lam = 0.f;
    if constexpr (MODE == 1) lam = lamp[0];

#pragma unroll
    for (int mi = 0; mi < 4; mi++)
#pragma unroll
        for (int ni = 0; ni < 4; ni++)
#pragma unroll
            for (int r = 0; r < 4; r++) {
                int m = m0 + wm + mi * 16 + quad * 4 + r;
                int n = n0 + wn + ni * 16 + l15;
                float val = acc[mi][ni][r];
                if constexpr (MODE == 0) {
                    Cout[(size_t)m * N + n] = val;
                } else {
                    if (n < NQK) {
                        Cout[(size_t)m * NQK + n] = val;
                    } else {
                        int f2 = n - NQK;
                        int hk = f2 >> 7, d = f2 & 127;
                        int b = m >> 11, t = m & (TT - 1);
                        size_t i1 = ((size_t)(b * HKV + hk) * TT + t) * DHD + d;
                        float vm = val + lam * (v1[i1] - val);
                        vT[((size_t)(b * HKV + hk) * DHD + d) * TT + t] = (bf16)vm;
                    }
                }
            }
}

// ---------------- RMSNorm + ortho RoPE, wave per (token, head) ----------------
// q heads get softmax scale * log2(e) pre-folded (fattn uses exp2).
__global__ void rmsrope(const float* __restrict__ Craw, const float* __restrict__ cosb,
                        const float* __restrict__ sinb, bf16* __restrict__ qb,
                        bf16* __restrict__ kb) {
    const float QSCALE = 0.08838834764831845f * 1.4426950408889634f;
    int gw = blockIdx.x * 4 + (threadIdx.x >> 6);
    int lane = threadIdx.x & 63;
    int token = gw / 20, hh = gw % 20;  // 0..15 q heads, 16..19 k heads
    int b = token >> 11, t = token & (TT - 1);
    int off = (hh < HH) ? hh * DHD : (HH * DHD + (hh - HH) * DHD);
    const float* src = Craw + (size_t)token * NQK + off;
    float2 xv = *(const float2*)(src + lane * 2);
    float x0 = xv.x, x1 = xv.y;
    float ss = x0 * x0 + x1 * x1;
#pragma unroll
    for (int m = 1; m < 64; m <<= 1) ss += __shfl_xor(ss, m);
    float r = rsqrtf(ss * (1.f / 128.f) + 1e-6f);
    if (hh < HH) r *= QSCALE;
    x0 *= r; x1 *= r;
    float c = cosb[t * 64 + lane], s = sinb[t * 64 + lane];
    float y0 = x0 * c - x1 * s;
    float y1 = x1 * c + x0 * s;
    bf16* dst = (hh < HH) ? (qb + ((size_t)(b * HH + hh) * TT + t) * DHD)
                          : (kb + ((size_t)(b * HKV + (hh - HH)) * TT + t) * DHD);
    dst[lane] = (bf16)y0;
    dst[64 + lane] = (bf16)y1;
}

// ---------------- gates = sigmoid(x[:, :16] @ gate_w^T) ----------------
__global__ void gatesk(const float* __restrict__ x, const float* __restrict__ gw,
                       float* __restrict__ gates) {
    __shared__ float gws[256];
    gws[threadIdx.x] = gw[threadIdx.x];
    __syncthreads();
    int idx = blockIdx.x * 256 + threadIdx.x;
    int h = idx & 15, token = idx >> 4;
    const float* xr = x + (size_t)token * DD;
    float z = 0.f;
#pragma unroll
    for (int j = 0; j < 16; j++) z += xr[j] * gws[h * 16 + j];
    gates[idx] = 1.f / (1.f + __expf(-z));
}

// ---------------- flash attention ----------------
// 256 blocks x 512 threads (8 waves -> 2 waves/SIMD). Block (b,h,g):
// wave-group A (waves 0-3) q-tiles {g, 31-g}; group B (waves 4-7) {15-g, 16+g}
// -> 33 subtile-steps per wave (balanced), SIMD pair (w,w+4) = one long + one
// short range. Waves 0-3 stage K, waves 4-7 stage VT (dbuf prefetch).
// S transposed (A=K, B=Q): P born in B-frag layout of 16x16x16 -> no LDS
// round-trip for PV. K/VT frags shared across the wave's 2 subtiles.
__global__ __launch_bounds__(512, 2) void fattn(const bf16* __restrict__ qbuf,
                                                const bf16* __restrict__ kbuf,
                                                const bf16* __restrict__ vt,
                                                const float* __restrict__ gates,
                                                bf16* __restrict__ yb) {
    // K  : [buf][kc:4][row:64][32]   (bf16)
    // VT : [buf][ni:4][d:128][16]    (bf16)
    __shared__ bf16 Ks[2][4 * 2048];
    __shared__ bf16 VTs[2][4 * 2048];

    const int bid = blockIdx.x;          // 256 blocks
    const int bh = bid & 31;             // b*16+h
    const int g = bid >> 5;              // 0..7
    const int h = bh & 15, b = bh >> 4;
    const int hk = h >> 2;
    const int tid = threadIdx.x, w = tid >> 6, lane = tid & 63;
    const int wq = w & 3, grp = w >> 2;
    const int l15 = lane & 15, quad = lane >> 4;

    const bf16* qbase = qbuf + ((size_t)(b * HH + h) * TT) * DHD;
    const bf16* kbase = kbuf + ((size_t)(b * HKV + hk) * TT) * DHD;
    const bf16* vtbase = vt + ((size_t)(b * HKV + hk) * DHD) * TT;

    const int Tq0 = grp ? (15 - g) : g;          // smaller tile
    const int Tq1 = grp ? (16 + g) : (31 - g);   // larger tile (= wave's max kt)
    const int ktmax_blk = 31 - g;

    // Q B-fragments (q = Tq*64 + wq*16 + l15, k = kc*32 + quad*8), read once
    bf16x8 qf0[4], qf1[4];
#pragma unroll
    for (int kc = 0; kc < 4; kc++) {
        qf0[kc] = *(const bf16x8*)(qbase + (size_t)(Tq0 * 64 + wq * 16 + l15) * DHD + kc * 32 + quad * 8);
        qf1[kc] = *(const bf16x8*)(qbase + (size_t)(Tq1 * 64 + wq * 16 + l15) * DHD + kc * 32 + quad * 8);
    }

    // diag mask: kg_off = ni*16 + quad*4 + r vs q_off = wq*16 + l15
    bool dm[4][4];
#pragma unroll
    for (int ni = 0; ni < 4; ni++)
#pragma unroll
        for (int r = 0; r < 4; r++)
            dm[ni][r] = (ni * 16 + quad * 4 + r) > (wq * 16 + l15);

    const int srow = lane >> 2;          // K staging: row within 16-group
    const int scg = (lane & 3) * 8;      // K staging: col offset
    const int vd = lane >> 1;            // VT staging: d within 32-group
    const int vh = (lane & 1) * 8;       // VT staging: t offset

    auto stage = [&](int kt, int buf) {
        if (grp == 0) {
#pragma unroll
            for (int i = 0; i < 4; i++)
                gl_lds16(kbase + (size_t)(kt * 64 + wq * 16 + srow) * DHD + i * 32 + scg,
                         &Ks[buf][i * 2048 + wq * 512]);
        } else {
#pragma unroll
            for (int i = 0; i < 4; i++)
                gl_lds16(vtbase + (size_t)(wq * 32 + vd) * TT + kt * 64 + i * 16 + vh,
                         &VTs[buf][i * 2048 + wq * 512]);
        }
    };

    stage(0, 0);

    f32x4 O0[8] = {}, O1[8] = {};
    float m0 = -INFINITY, l0 = 0.f, m1 = -INFINITY, l1 = 0.f;

    for (int kt = 0; kt <= ktmax_blk; kt++) {
        int cur = kt & 1;
        __syncthreads();                 // drains prefetch into buf `cur`
        if (kt < ktmax_blk) stage(kt + 1, cur ^ 1);

        if (kt > Tq1) continue;          // wave done computing; still stages+barriers
        const bool a0 = (kt <= Tq0);

        // S^T = K Q^T, kf loaded per-ni (16 regs live), shared by both subtiles
        f32x4 s0[4], s1[4];
#pragma unroll
        for (int ni = 0; ni < 4; ni++) {
            bf16x8 kfl[4];
#pragma unroll
            for (int kc = 0; kc < 4; kc++)
                kfl[kc] = *(const bf16x8*)(&Ks[cur][kc * 2048 + (ni * 16 + l15) * 32 + quad * 8]);
            f32x4 z1 = {};
#pragma unroll
            for (int kc = 0; kc < 4; kc++)
                z1 = __builtin_amdgcn_mfma_f32_16x16x32_bf16(kfl[kc], qf1[kc], z1, 0, 0, 0);
            s1[ni] = z1;
            if (a0) {
                f32x4 z0 = {};
#pragma unroll
                for (int kc = 0; kc < 4; kc++)
                    z0 = __builtin_amdgcn_mfma_f32_16x16x32_bf16(kfl[kc], qf0[kc], z0, 0, 0, 0);
                s0[ni] = z0;
            }
        }

        short4v bp0[4], bp1[4];

        // softmax subtile 1 (always active here)
        {
            if (kt == Tq1) {
#pragma unroll
                for (int ni = 0; ni < 4; ni++)
#pragma unroll
                    for (int r = 0; r < 4; r++)
                        if (dm[ni][r]) s1[ni][r] = -INFINITY;
            }
            float mx = s1[0][0];
#pragma unroll
            for (int ni = 0; ni < 4; ni++)
#pragma unroll
                for (int r = 0; r < 4; r++) mx = fmaxf(mx, s1[ni][r]);
            mx = fmaxf(mx, __shfl_xor(mx, 16));
            mx = fmaxf(mx, __shfl_xor(mx, 32));
            float mold = m1, mnew = fmaxf(mold, mx);
            float rs = 0.f;
#pragma unroll
            for (int ni = 0; ni < 4; ni++) {
                union { bf16x4 hv; short4v sv4; } u;
#pragma unroll
                for (int r = 0; r < 4; r++) {
                    float pe = __builtin_amdgcn_exp2f(s1[ni][r] - mnew);
                    u.hv[r] = (bf16)pe;
                    rs += pe;
                }
                bp1[ni] = u.sv4;
            }
            rs += __shfl_xor(rs, 16);
            rs += __shfl_xor(rs, 32);
            if (__any(mnew > mold)) {
                float al = __builtin_amdgcn_exp2f(mold - mnew);
                l1 *= al;
#pragma unroll
                for (int dn = 0; dn < 8; dn++)
#pragma unroll
                    for (int r = 0; r < 4; r++) O1[dn][r] *= al;
            }
            l1 += rs;
            m1 = mnew;
        }
        // softmax subtile 0
        if (a0) {
            if (kt == Tq0) {
#pragma unroll
                for (int ni = 0; ni < 4; ni++)
#pragma unroll
                    for (int r = 0; r < 4; r++)
                        if (dm[ni][r]) s0[ni][r] = -INFINITY;
            }
            float mx = s0[0][0];
#pragma unroll
            for (int ni = 0; ni < 4; ni++)
#pragma unroll
                for (int r = 0; r < 4; r++) mx = fmaxf(mx, s0[ni][r]);
            mx = fmaxf(mx, __shfl_xor(mx, 16));
            mx = fmaxf(mx, __shfl_xor(mx, 32));
            float mold = m0, mnew = fmaxf(mold, mx);
            float rs = 0.f;
#pragma unroll
            for (int ni = 0; ni < 4; ni++) {
                union { bf16x4 hv; short4v sv4; } u;
#pragma unroll
                for (int r = 0; r < 4; r++) {
                    float pe = __builtin_amdgcn_exp2f(s0[ni][r] - mnew);
                    u.hv[r] = (bf16)pe;
                    rs += pe;
                }
                bp0[ni] = u.sv4;
            }
            rs += __shfl_xor(rs, 16);
            rs += __shfl_xor(rs, 32);
            if (__any(mnew > mold)) {
                float al = __builtin_amdgcn_exp2f(mold - mnew);
                l0 *= al;
#pragma unroll
                for (int dn = 0; dn < 8; dn++)
#pragma unroll
                    for (int r = 0; r < 4; r++) O0[dn][r] *= al;
            }
            l0 += rs;
            m0 = mnew;
        }

        // PV: O^T += VT * P^T, vf per-ni shared by both subtiles
#pragma unroll
        for (int ni = 0; ni < 4; ni++) {
            short4v vfl[8];
#pragma unroll
            for (int dn = 0; dn < 8; dn++)
                vfl[dn] = *(const short4v*)(&VTs[cur][ni * 2048 + (dn * 16 + l15) * 16 + quad * 4]);
#pragma unroll
            for (int dn = 0; dn < 8; dn++)
                O1[dn] = mfma16bf16(vfl[dn], bp1[ni], O1[dn]);
            if (a0) {
#pragma unroll
                for (int dn = 0; dn < 8; dn++)
                    O0[dn] = mfma16bf16(vfl[dn], bp0[ni], O0[dn]);
            }
        }
    }

    // epilogue: O^T/l * gate -> yb (B,T,H*DH) bf16
    auto epi = [&](const f32x4* Oc, float lsum, int qt) {
        int qg = qt * 64 + wq * 16 + l15;
        float gi = gates[((size_t)b * TT + qg) * HH + h] / lsum;
#pragma unroll
        for (int dn = 0; dn < 8; dn++) {
            bf16x4 o;
#pragma unroll
            for (int r = 0; r < 4; r++) o[r] = (bf16)(Oc[dn][r] * gi);
            *(bf16x4*)(yb + ((size_t)(b * TT + qg) * HH + h) * DHD + dn * 16 + quad * 4) = o;
        }
    };
    epi(O0, l0, Tq0);
    epi(O1, l1, Tq1);
}

extern "C" void kernel_launch(void* const* d_in, const int* in_sizes, int n_in,
                              void* d_out, int out_size, void* d_ws, size_t ws_size,
                              hipStream_t stream) {
    const float* x    = (const float*)d_in[0];
    const float* cosb = (const float*)d_in[2];
    const float* sinb = (const float*)d_in[3];
    const float* v1   = (const float*)d_in[4];
    const float* Wq   = (const float*)d_in[5];
    const float* Wk   = (const float*)d_in[6];
    const float* Wv   = (const float*)d_in[7];
    const float* Wo   = (const float*)d_in[8];
    const float* gw   = (const float*)d_in[9];
    const float* lam  = (const float*)d_in[10];
    float* out = (float*)d_out;

    char* ws = (char*)d_ws;
    bf16* xb     = (bf16*)(ws);                   // 16,777,216 B (reused later by yb)
    bf16* wqkvb  = (bf16*)(ws + 16777216);        // 12,582,912
    bf16* wob    = (bf16*)(ws + 29360128);        //  8,388,608
    float* Craw  = (float*)(ws + 37748736);       // 41,943,040 (4096 x 2560 fp32)
    bf16* qb     = (bf16*)(ws + 79691776);        // 16,777,216
    bf16* kb     = (bf16*)(ws + 96468992);        //  4,194,304
    bf16* vtb    = (bf16*)(ws + 100663296);       //  4,194,304
    float* gts   = (float*)(ws + 104857600);      //    262,144
    bf16* yb     = xb;                            // alias: xb dead after QKV GEMM

    // converts
    cvt_bf16<<<4096, 256, 0, stream>>>(x, xb, 1048576);
    cvt_bf16<<<2048, 256, 0, stream>>>(Wq, wqkvb, 524288);
    cvt_bf16<<<512, 256, 0, stream>>>(Wk, wqkvb + 4194304, 131072);
    cvt_bf16<<<512, 256, 0, stream>>>(Wv, wqkvb + 5242880, 131072);
    cvt_bf16<<<2048, 256, 0, stream>>>(Wo, wob, 524288);

    // QKV projection (writes Craw for q/k, mixed+transposed bf16 V)
    gemm_bt<1><<<dim3(24, 32), 256, 0, stream>>>(xb, wqkvb, 4096, NQKV, 2048,
                                                 Craw, vtb, v1, lam);
    // rmsnorm + rope -> bf16 q/k (q pre-scaled by scale*log2e)
    rmsrope<<<20480, 256, 0, stream>>>(Craw, cosb, sinb, qb, kb);
    // gates
    gatesk<<<256, 256, 0, stream>>>(x, gw, gts);
    // flash attention (8 waves/block, 2 subtiles/wave) -- yb aliases xb
    fattn<<<256, 512, 0, stream>>>(qb, kb, vtb, gts, yb);
    // output projection
    gemm_bt<0><<<dim3(16, 32), 256, 0, stream>>>(yb, wob, 4096, 2048, 2048,
                                                 out, nullptr, nullptr, nullptr);
    // v1 passthrough (second tuple output)
    (void)hipMemcpyAsync(out + 8388608, v1, (size_t)2097152 * sizeof(float),
                         hipMemcpyDeviceToDevice, stream);
}

// Round 6
// 339.676 us; speedup vs baseline: 1.2611x; 1.1793x over previous
//
#include <hip/hip_runtime.h>

typedef __bf16 bf16;
typedef __attribute__((ext_vector_type(8))) __bf16 bf16x8;
typedef __attribute__((ext_vector_type(4))) __bf16 bf16x4;
typedef __attribute__((ext_vector_type(4))) float f32x4;
typedef __attribute__((ext_vector_type(4))) short short4v;
typedef __attribute__((ext_vector_type(4))) unsigned int u32x4;

// ---- constants for this problem ----
#define BB 2
#define TT 2048
#define DD 2048
#define HH 16
#define HKV 4
#define DHD 128
#define NQKV 3072   // H*DH + 2*HKV*DH

__device__ __forceinline__ void gl_lds16(const bf16* g, bf16* l) {
    __builtin_amdgcn_global_load_lds(
        (const __attribute__((address_space(1))) void*)g,
        (__attribute__((address_space(3))) void*)l, 16, 0, 0);
}

__device__ __forceinline__ f32x4 mfma16bf16(short4v a, short4v b, f32x4 c) {
#if defined(__HIP_DEVICE_COMPILE__)
    return __builtin_amdgcn_mfma_f32_16x16x16bf16_1k(a, b, c, 0, 0, 0);
#else
    return c;  // host pass never executes device code
#endif
}

// ---------------- fp32 -> bf16 convert ----------------
__global__ void cvt_bf16(const float* __restrict__ src, bf16* __restrict__ dst, int n8) {
    int i = blockIdx.x * 256 + threadIdx.x;
    if (i >= n8) return;
    float4 a = ((const float4*)src)[i * 2];
    float4 b = ((const float4*)src)[i * 2 + 1];
    bf16x8 v;
    v[0] = (bf16)a.x; v[1] = (bf16)a.y; v[2] = (bf16)a.z; v[3] = (bf16)a.w;
    v[4] = (bf16)b.x; v[5] = (bf16)b.y; v[6] = (bf16)b.z; v[7] = (bf16)b.w;
    *(bf16x8*)(dst + (size_t)i * 8) = v;
}

// ---------------- GEMM: C = A(MxK) * Bw(NxK)^T, bf16 in, fp32 acc, BK=64 ----------------
// MODE 0: plain fp32 store to Cout (ld = N).
// MODE 1: QKV fused epilogue. Each 128-col block tile is one head:
//   hid = n0>>7: 0-15 q heads (rmsnorm+rope+QSCALE -> qb), 16-19 k heads
//   (rmsnorm+rope -> kb), 20-23 v heads (v1-mix -> transposed vtb).
//   All outputs staged through an LDS transpose buffer for coalesced stores.
template <int MODE>
__global__ void gemm_bt(const bf16* __restrict__ A, const bf16* __restrict__ Bw,
                        int M, int N, int K,
                        float* __restrict__ Cout,
                        bf16* __restrict__ qb, bf16* __restrict__ kb,
                        bf16* __restrict__ vtb,
                        const float* __restrict__ v1,
                        const float* __restrict__ cosb,
                        const float* __restrict__ sinb,
                        const float* __restrict__ lamp) {
    constexpr int SMEM_ELE = (MODE == 1) ? 17920 : 16384;  // bf16 elements
    __shared__ bf16 smem[SMEM_ELE];
    bf16* As = smem;          // [kc2:2][rc:8][16 rows][32 k] = 8192 ele
    bf16* Bs = smem + 8192;
    const int tid = threadIdx.x;
    const int w = tid >> 6, lane = tid & 63;
    const int l15 = lane & 15, quad = lane >> 4;
    const int m0 = blockIdx.y * 128, n0 = blockIdx.x * 128;
    const int wm = (w & 1) * 64, wn = (w >> 1) * 64;

    f32x4 acc[4][4] = {};
    const int lrow = lane >> 2;          // 0..15 row within chunk
    const int lcol = (lane & 3) * 8;     // bf16 col offset

    for (int k0 = 0; k0 < K; k0 += 64) {
#pragma unroll
        for (int i = 0; i < 4; i++) {
            int c = w * 4 + i;           // 0..15
            int kc2 = c >> 3, rc = c & 7;
            int row = rc * 16 + lrow;
            int kk = k0 + kc2 * 32 + lcol;
            gl_lds16(A + (size_t)(m0 + row) * K + kk, As + c * 512);
            gl_lds16(Bw + (size_t)(n0 + row) * K + kk, Bs + c * 512);
        }
        __syncthreads();
#pragma unroll
        for (int kc2 = 0; kc2 < 2; kc2++) {
            bf16x8 af[4], bfr[4];
#pragma unroll
            for (int mi = 0; mi < 4; mi++)
                af[mi] = *(const bf16x8*)(As + kc2 * 4096 + ((wm >> 4) + mi) * 512 + l15 * 32 + quad * 8);
#pragma unroll
            for (int ni = 0; ni < 4; ni++)
                bfr[ni] = *(const bf16x8*)(Bs + kc2 * 4096 + ((wn >> 4) + ni) * 512 + l15 * 32 + quad * 8);
#pragma unroll
            for (int mi = 0; mi < 4; mi++)
#pragma unroll
                for (int ni = 0; ni < 4; ni++)
                    acc[mi][ni] = __builtin_amdgcn_mfma_f32_16x16x32_bf16(af[mi], bfr[ni], acc[mi][ni], 0, 0, 0);
        }
        __syncthreads();
    }

    if constexpr (MODE == 0) {
#pragma unroll
        for (int mi = 0; mi < 4; mi++)
#pragma unroll
            for (int ni = 0; ni < 4; ni++)
#pragma unroll
                for (int r = 0; r < 4; r++) {
                    int m = m0 + wm + mi * 16 + quad * 4 + r;
                    int n = n0 + wn + ni * 16 + l15;
                    Cout[(size_t)m * N + n] = acc[mi][ni][r];
                }
    } else {
        const int hid = n0 >> 7;         // 0..23
        const int b = m0 >> 11;
        const int t0 = m0 & (TT - 1);
        bf16* ep = smem;                 // [128 rows][136] transpose buffer

        if (hid < 20) {
            // ---- rmsnorm partials (per row, across the 128-col head) ----
            float* ssum = (float*)(smem + 17408);   // [2][128] fp32
            float ssq[4][4];
#pragma unroll
            for (int mi = 0; mi < 4; mi++)
#pragma unroll
                for (int r = 0; r < 4; r++) {
                    float s = 0.f;
#pragma unroll
                    for (int ni = 0; ni < 4; ni++) {
                        float v = acc[mi][ni][r];
                        s += v * v;
                    }
                    s += __shfl_xor(s, 1);
                    s += __shfl_xor(s, 2);
                    s += __shfl_xor(s, 4);
                    s += __shfl_xor(s, 8);
                    ssq[mi][r] = s;
                }
            if (l15 == 0) {
#pragma unroll
                for (int mi = 0; mi < 4; mi++)
#pragma unroll
                    for (int r = 0; r < 4; r++)
                        ssum[(wn >> 6) * 128 + wm + mi * 16 + quad * 4 + r] = ssq[mi][r];
            }
            __syncthreads();
            const float QSCALE = 0.08838834764831845f * 1.4426950408889634f;
            float rn[4][4];
#pragma unroll
            for (int mi = 0; mi < 4; mi++)
#pragma unroll
                for (int r = 0; r < 4; r++) {
                    int row = wm + mi * 16 + quad * 4 + r;
                    float ss = ssum[row] + ssum[128 + row];
                    float rv = rsqrtf(ss * (1.f / 128.f) + 1e-6f);
                    if (hid < HH) rv *= QSCALE;
                    rn[mi][r] = rv;
                }
            // ---- rope -> ep[t_local][outcol] ----
#pragma unroll
            for (int mi = 0; mi < 4; mi++)
#pragma unroll
                for (int ni = 0; ni < 4; ni++)
#pragma unroll
                    for (int r = 0; r < 4; r++) {
                        float sv = acc[mi][ni][r] * rn[mi][r];
                        float pv = __shfl_xor(sv, 1);
                        int nl = wn + ni * 16 + l15;       // 0..127
                        int j = nl >> 1;                   // 0..63
                        int tl = wm + mi * 16 + quad * 4 + r;
                        float c = cosb[(size_t)(t0 + tl) * 64 + j];
                        float s = sinb[(size_t)(t0 + tl) * 64 + j];
                        float o = (nl & 1) ? (sv * c + pv * s) : (sv * c - pv * s);
                        int oc = (nl & 1) ? (64 + j) : j;
                        ep[tl * 136 + oc] = (bf16)o;
                    }
            __syncthreads();
            bf16* dst = (hid < HH)
                ? (qb + ((size_t)(b * HH + hid) * TT + t0) * DHD)
                : (kb + ((size_t)(b * HKV + (hid - HH)) * TT + t0) * DHD);
            int tl = tid >> 1, half = tid & 1;
#pragma unroll
            for (int c8 = 0; c8 < 8; c8++)
                *(bf16x8*)(dst + (size_t)tl * DHD + half * 64 + c8 * 8) =
                    *(const bf16x8*)(ep + tl * 136 + half * 64 + c8 * 8);
        } else {
            // ---- v: mix with v1, transpose -> vtb (B,HKV,DH,T) ----
            float lam = lamp[0];
            int vh = hid - 20;
            const float* v1b = v1 + ((size_t)(b * HKV + vh) * TT) * DHD;
#pragma unroll
            for (int mi = 0; mi < 4; mi++)
#pragma unroll
                for (int ni = 0; ni < 4; ni++)
#pragma unroll
                    for (int r = 0; r < 4; r++) {
                        int d = wn + ni * 16 + l15;
                        int tl = wm + mi * 16 + quad * 4 + r;
                        float val = acc[mi][ni][r];
                        float vm = val + lam * (v1b[(size_t)(t0 + tl) * DHD + d] - val);
                        ep[d * 136 + tl] = (bf16)vm;
                    }
            __syncthreads();
            bf16* dstv = vtb + ((size_t)(b * HKV + vh) * DHD) * TT + t0;
            int dd = tid >> 1, half = tid & 1;
#pragma unroll
            for (int c8 = 0; c8 < 8; c8++)
                *(bf16x8*)(dstv + (size_t)dd * TT + half * 64 + c8 * 8) =
                    *(const bf16x8*)(ep + dd * 136 + half * 64 + c8 * 8);
        }
    }
}

// ---------------- gates = sigmoid(x[:, :16] @ gate_w^T) ----------------
__global__ void gatesk(const float* __restrict__ x, const float* __restrict__ gw,
                       float* __restrict__ gates) {
    __shared__ float gws[256];
    gws[threadIdx.x] = gw[threadIdx.x];
    __syncthreads();
    int idx = blockIdx.x * 256 + threadIdx.x;
    int h = idx & 15, token = idx >> 4;
    const float* xr = x + (size_t)token * DD;
    float z = 0.f;
#pragma unroll
    for (int j = 0; j < 16; j++) z += xr[j] * gws[h * 16 + j];
    gates[idx] = 1.f / (1.f + __expf(-z));
}

// ---------------- flash attention (unchanged from R5) ----------------
__global__ __launch_bounds__(512, 2) void fattn(const bf16* __restrict__ qbuf,
                                                const bf16* __restrict__ kbuf,
                                                const bf16* __restrict__ vt,
                                                const float* __restrict__ gates,
                                                bf16* __restrict__ yb) {
    __shared__ bf16 Ks[2][4 * 2048];
    __shared__ bf16 VTs[2][4 * 2048];

    const int bid = blockIdx.x;          // 256 blocks
    const int bh = bid & 31;             // b*16+h
    const int g = bid >> 5;              // 0..7
    const int h = bh & 15, b = bh >> 4;
    const int hk = h >> 2;
    const int tid = threadIdx.x, w = tid >> 6, lane = tid & 63;
    const int wq = w & 3, grp = w >> 2;
    const int l15 = lane & 15, quad = lane >> 4;

    const bf16* qbase = qbuf + ((size_t)(b * HH + h) * TT) * DHD;
    const bf16* kbase = kbuf + ((size_t)(b * HKV + hk) * TT) * DHD;
    const bf16* vtbase = vt + ((size_t)(b * HKV + hk) * DHD) * TT;

    const int Tq0 = grp ? (15 - g) : g;
    const int Tq1 = grp ? (16 + g) : (31 - g);
    const int ktmax_blk = 31 - g;

    bf16x8 qf0[4], qf1[4];
#pragma unroll
    for (int kc = 0; kc < 4; kc++) {
        qf0[kc] = *(const bf16x8*)(qbase + (size_t)(Tq0 * 64 + wq * 16 + l15) * DHD + kc * 32 + quad * 8);
        qf1[kc] = *(const bf16x8*)(qbase + (size_t)(Tq1 * 64 + wq * 16 + l15) * DHD + kc * 32 + quad * 8);
    }

    bool dm[4][4];
#pragma unroll
    for (int ni = 0; ni < 4; ni++)
#pragma unroll
        for (int r = 0; r < 4; r++)
            dm[ni][r] = (ni * 16 + quad * 4 + r) > (wq * 16 + l15);

    const int srow = lane >> 2;
    const int scg = (lane & 3) * 8;
    const int vd = lane >> 1;
    const int vh = (lane & 1) * 8;

    auto stage = [&](int kt, int buf) {
        if (grp == 0) {
#pragma unroll
            for (int i = 0; i < 4; i++)
                gl_lds16(kbase + (size_t)(kt * 64 + wq * 16 + srow) * DHD + i * 32 + scg,
                         &Ks[buf][i * 2048 + wq * 512]);
        } else {
#pragma unroll
            for (int i = 0; i < 4; i++)
                gl_lds16(vtbase + (size_t)(wq * 32 + vd) * TT + kt * 64 + i * 16 + vh,
                         &VTs[buf][i * 2048 + wq * 512]);
        }
    };

    stage(0, 0);

    f32x4 O0[8] = {}, O1[8] = {};
    float m0 = -INFINITY, l0 = 0.f, m1 = -INFINITY, l1 = 0.f;

    for (int kt = 0; kt <= ktmax_blk; kt++) {
        int cur = kt & 1;
        __syncthreads();
        if (kt < ktmax_blk) stage(kt + 1, cur ^ 1);

        if (kt > Tq1) continue;
        const bool a0 = (kt <= Tq0);

        f32x4 s0[4], s1[4];
#pragma unroll
        for (int ni = 0; ni < 4; ni++) {
            bf16x8 kfl[4];
#pragma unroll
            for (int kc = 0; kc < 4; kc++)
                kfl[kc] = *(const bf16x8*)(&Ks[cur][kc * 2048 + (ni * 16 + l15) * 32 + quad * 8]);
            f32x4 z1 = {};
#pragma unroll
            for (int kc = 0; kc < 4; kc++)
                z1 = __builtin_amdgcn_mfma_f32_16x16x32_bf16(kfl[kc], qf1[kc], z1, 0, 0, 0);
            s1[ni] = z1;
            if (a0) {
                f32x4 z0 = {};
#pragma unroll
                for (int kc = 0; kc < 4; kc++)
                    z0 = __builtin_amdgcn_mfma_f32_16x16x32_bf16(kfl[kc], qf0[kc], z0, 0, 0, 0);
                s0[ni] = z0;
            }
        }

        short4v bp0[4], bp1[4];
        {
            if (kt == Tq1) {
#pragma unroll
                for (int ni = 0; ni < 4; ni++)
#pragma unroll
                    for (int r = 0; r < 4; r++)
                        if (dm[ni][r]) s1[ni][r] = -INFINITY;
            }
            float mx = s1[0][0];
#pragma unroll
            for (int ni = 0; ni < 4; ni++)
#pragma unroll
                for (int r = 0; r < 4; r++) mx = fmaxf(mx, s1[ni][r]);
            mx = fmaxf(mx, __shfl_xor(mx, 16));
            mx = fmaxf(mx, __shfl_xor(mx, 32));
            float mold = m1, mnew = fmaxf(mold, mx);
            float rs = 0.f;
#pragma unroll
            for (int ni = 0; ni < 4; ni++) {
                union { bf16x4 hv; short4v sv4; } u;
#pragma unroll
                for (int r = 0; r < 4; r++) {
                    float pe = __builtin_amdgcn_exp2f(s1[ni][r] - mnew);
                    u.hv[r] = (bf16)pe;
                    rs += pe;
                }
                bp1[ni] = u.sv4;
            }
            rs += __shfl_xor(rs, 16);
            rs += __shfl_xor(rs, 32);
            if (__any(mnew > mold)) {
                float al = __builtin_amdgcn_exp2f(mold - mnew);
                l1 *= al;
#pragma unroll
                for (int dn = 0; dn < 8; dn++)
#pragma unroll
                    for (int r = 0; r < 4; r++) O1[dn][r] *= al;
            }
            l1 += rs;
            m1 = mnew;
        }
        if (a0) {
            if (kt == Tq0) {
#pragma unroll
                for (int ni = 0; ni < 4; ni++)
#pragma unroll
                    for (int r = 0; r < 4; r++)
                        if (dm[ni][r]) s0[ni][r] = -INFINITY;
            }
            float mx = s0[0][0];
#pragma unroll
            for (int ni = 0; ni < 4; ni++)
#pragma unroll
                for (int r = 0; r < 4; r++) mx = fmaxf(mx, s0[ni][r]);
            mx = fmaxf(mx, __shfl_xor(mx, 16));
            mx = fmaxf(mx, __shfl_xor(mx, 32));
            float mold = m0, mnew = fmaxf(mold, mx);
            float rs = 0.f;
#pragma unroll
            for (int ni = 0; ni < 4; ni++) {
                union { bf16x4 hv; short4v sv4; } u;
#pragma unroll
                for (int r = 0; r < 4; r++) {
                    float pe = __builtin_amdgcn_exp2f(s0[ni][r] - mnew);
                    u.hv[r] = (bf16)pe;
                    rs += pe;
                }
                bp0[ni] = u.sv4;
            }
            rs += __shfl_xor(rs, 16);
            rs += __shfl_xor(rs, 32);
            if (__any(mnew > mold)) {
                float al = __builtin_amdgcn_exp2f(mold - mnew);
                l0 *= al;
#pragma unroll
                for (int dn = 0; dn < 8; dn++)
#pragma unroll
                    for (int r = 0; r < 4; r++) O0[dn][r] *= al;
            }
            l0 += rs;
            m0 = mnew;
        }

#pragma unroll
        for (int ni = 0; ni < 4; ni++) {
            short4v vfl[8];
#pragma unroll
            for (int dn = 0; dn < 8; dn++)
                vfl[dn] = *(const short4v*)(&VTs[cur][ni * 2048 + (dn * 16 + l15) * 16 + quad * 4]);
#pragma unroll
            for (int dn = 0; dn < 8; dn++)
                O1[dn] = mfma16bf16(vfl[dn], bp1[ni], O1[dn]);
            if (a0) {
#pragma unroll
                for (int dn = 0; dn < 8; dn++)
                    O0[dn] = mfma16bf16(vfl[dn], bp0[ni], O0[dn]);
            }
        }
    }

    auto epi = [&](const f32x4* Oc, float lsum, int qt) {
        int qg = qt * 64 + wq * 16 + l15;
        float gi = gates[((size_t)b * TT + qg) * HH + h] / lsum;
#pragma unroll
        for (int dn = 0; dn < 8; dn++) {
            bf16x4 o;
#pragma unroll
            for (int r = 0; r < 4; r++) o[r] = (bf16)(Oc[dn][r] * gi);
            *(bf16x4*)(yb + ((size_t)(b * TT + qg) * HH + h) * DHD + dn * 16 + quad * 4) = o;
        }
    };
    epi(O0, l0, Tq0);
    epi(O1, l1, Tq1);
}

extern "C" void kernel_launch(void* const* d_in, const int* in_sizes, int n_in,
                              void* d_out, int out_size, void* d_ws, size_t ws_size,
                              hipStream_t stream) {
    const float* x    = (const float*)d_in[0];
    const float* cosb = (const float*)d_in[2];
    const float* sinb = (const float*)d_in[3];
    const float* v1   = (const float*)d_in[4];
    const float* Wq   = (const float*)d_in[5];
    const float* Wk   = (const float*)d_in[6];
    const float* Wv   = (const float*)d_in[7];
    const float* Wo   = (const float*)d_in[8];
    const float* gw   = (const float*)d_in[9];
    const float* lam  = (const float*)d_in[10];
    float* out = (float*)d_out;

    char* ws = (char*)d_ws;
    bf16* xb     = (bf16*)(ws);                   // 16,777,216 B (reused later by yb)
    bf16* wqkvb  = (bf16*)(ws + 16777216);        // 12,582,912
    bf16* wob    = (bf16*)(ws + 29360128);        //  8,388,608
    bf16* qb     = (bf16*)(ws + 79691776);        // 16,777,216
    bf16* kb     = (bf16*)(ws + 96468992);        //  4,194,304
    bf16* vtb    = (bf16*)(ws + 100663296);       //  4,194,304
    float* gts   = (float*)(ws + 104857600);      //    262,144
    bf16* yb     = xb;                            // alias: xb dead after QKV GEMM

    // converts
    cvt_bf16<<<4096, 256, 0, stream>>>(x, xb, 1048576);
    cvt_bf16<<<2048, 256, 0, stream>>>(Wq, wqkvb, 524288);
    cvt_bf16<<<512, 256, 0, stream>>>(Wk, wqkvb + 4194304, 131072);
    cvt_bf16<<<512, 256, 0, stream>>>(Wv, wqkvb + 5242880, 131072);
    cvt_bf16<<<2048, 256, 0, stream>>>(Wo, wob, 524288);

    // QKV projection + fused rmsnorm/rope/v-mix epilogues
    gemm_bt<1><<<dim3(24, 32), 256, 0, stream>>>(xb, wqkvb, 4096, NQKV, 2048,
                                                 nullptr, qb, kb, vtb, v1,
                                                 cosb, sinb, lam);
    // gates
    gatesk<<<256, 256, 0, stream>>>(x, gw, gts);
    // flash attention -- yb aliases xb
    fattn<<<256, 512, 0, stream>>>(qb, kb, vtb, gts, yb);
    // output projection
    gemm_bt<0><<<dim3(16, 32), 256, 0, stream>>>(yb, wob, 4096, 2048, 2048,
                                                 out, nullptr, nullptr, nullptr,
                                                 nullptr, nullptr, nullptr, nullptr);
    // v1 passthrough (second tuple output)
    (void)hipMemcpyAsync(out + 8388608, v1, (size_t)2097152 * sizeof(float),
                         hipMemcpyDeviceToDevice, stream);
}